// Round 5
// baseline (121.687 us; speedup 1.0000x reference)
//
#include <hip/hip_runtime.h>
#include <math.h>

// GaussianNLLLoss: out = -mean( c0 + log(normcdf(-lambda*resid/sigma)) - resid^2/(2*sigma2) )
// R5: one-shot straight-line threads. R4 lesson: compiler collapsed the manual
// double-buffer (VGPR=48, not 128+) and waves stay convoy-locked in the loop
// (VALUBusy pinned at 27%, dur ~= mem-phase + compute-phase serialized).
// Now: 8192 blocks x 256 thr, each thread does exactly 8 dwordx4 loads
// (4 yp + 4 yt, interleaved) then 16 elements of compute -- no loop, natural
// vmcnt staircase, block churn staggers memory/compute phases across the CU.

__device__ __forceinline__ float ll_elem(float r, float karg, float nk2, float inv2s2) {
    float r2 = r * r;
    float x  = karg * r;
    float ax = fabsf(x);
    float t  = __builtin_amdgcn_rcpf(fmaf(0.3275911f, ax, 1.0f));  // v_rcp_f32
    float p  = fmaf(t, 1.061405429f, -1.453152027f);
    p = fmaf(t, p, 1.421413741f);
    p = fmaf(t, p, -0.284496736f);
    p = fmaf(t, p, 0.254829592f);
    p *= t;
    float e  = __expf(nk2 * r2);                 // exp(-x^2), reusing r^2
    float ea = fmaf(-p, e, 1.0f);                // erf(|x|)  (A&S 7.1.26, |err|<1.5e-7)
    float ev = copysignf(ea, x);                 // erf(x)
    return __logf(fmaf(0.5f, ev, 0.5f)) - r2 * inv2s2;  // log(ncdf) - r^2/(2s2)
}

__global__ __launch_bounds__(256) void gnll_kernel(
    const float4* __restrict__ yp, const float4* __restrict__ yt,
    const float* __restrict__ lsv, const float* __restrict__ lsu,
    float* __restrict__ out, int n4, float neg_inv_n)
{
    const float std_v  = __expf(lsv[0]);
    const float std_u  = __expf(lsu[0]);
    const float sigma2 = std_v * std_v + std_u * std_u;
    const float sigma  = sqrtf(sigma2);
    const float llamda = std_u / std_v;
    const float karg   = -llamda / sigma * 0.70710678118654752f;  // *r -> erf arg
    const float nk2    = -karg * karg;                            // *r^2 -> -x^2
    const float c0     = -0.5f * logf(1.57079632679489662f)
                         - 0.5f * logf(sigma2);
    const float inv2s2 = 0.5f / sigma2;

    const int tid = blockIdx.x * blockDim.x + threadIdx.x;
    const int nth = gridDim.x * blockDim.x;

    float acc = 0.0f;

    const int i0 = tid;
    const int i1 = tid + nth;
    const int i2 = tid + 2 * nth;
    const int i3 = tid + 3 * nth;

    if (i3 < n4) {
        // Fast path (whole grid for the bench shape): 8 independent dwordx4
        // loads issued back-to-back, consumed in issue order.
        float4 p0 = yp[i0];
        float4 t0 = yt[i0];
        float4 p1 = yp[i1];
        float4 t1 = yt[i1];
        float4 p2 = yp[i2];
        float4 t2 = yt[i2];
        float4 p3 = yp[i3];
        float4 t3 = yt[i3];

        float s0 = ll_elem(t0.x - p0.x, karg, nk2, inv2s2)
                 + ll_elem(t0.y - p0.y, karg, nk2, inv2s2)
                 + ll_elem(t0.z - p0.z, karg, nk2, inv2s2)
                 + ll_elem(t0.w - p0.w, karg, nk2, inv2s2);
        float s1 = ll_elem(t1.x - p1.x, karg, nk2, inv2s2)
                 + ll_elem(t1.y - p1.y, karg, nk2, inv2s2)
                 + ll_elem(t1.z - p1.z, karg, nk2, inv2s2)
                 + ll_elem(t1.w - p1.w, karg, nk2, inv2s2);
        float s2 = ll_elem(t2.x - p2.x, karg, nk2, inv2s2)
                 + ll_elem(t2.y - p2.y, karg, nk2, inv2s2)
                 + ll_elem(t2.z - p2.z, karg, nk2, inv2s2)
                 + ll_elem(t2.w - p2.w, karg, nk2, inv2s2);
        float s3 = ll_elem(t3.x - p3.x, karg, nk2, inv2s2)
                 + ll_elem(t3.y - p3.y, karg, nk2, inv2s2)
                 + ll_elem(t3.z - p3.z, karg, nk2, inv2s2)
                 + ll_elem(t3.w - p3.w, karg, nk2, inv2s2);
        acc = (s0 + s1) + (s2 + s3) + 16.0f * c0;
    } else {
        // Generic tail (unused at the bench shape)
        int cnt = 0;
        for (int i = i0; i < n4; i += nth) {
            float4 p = yp[i];
            float4 t = yt[i];
            acc += ll_elem(t.x - p.x, karg, nk2, inv2s2)
                 + ll_elem(t.y - p.y, karg, nk2, inv2s2)
                 + ll_elem(t.z - p.z, karg, nk2, inv2s2)
                 + ll_elem(t.w - p.w, karg, nk2, inv2s2);
            cnt += 4;
        }
        acc = fmaf((float)cnt, c0, acc);
    }

    // wave64 butterfly reduce
    #pragma unroll
    for (int off = 32; off > 0; off >>= 1)
        acc += __shfl_down(acc, off, 64);

    __shared__ float ws[4];
    int lane = threadIdx.x & 63;
    int wid  = threadIdx.x >> 6;
    if (lane == 0) ws[wid] = acc;
    __syncthreads();
    if (threadIdx.x == 0) {
        float s = (ws[0] + ws[1]) + (ws[2] + ws[3]);
        atomicAdd(out, s * neg_inv_n);
    }
}

extern "C" void kernel_launch(void* const* d_in, const int* in_sizes, int n_in,
                              void* d_out, int out_size, void* d_ws, size_t ws_size,
                              hipStream_t stream) {
    const float4* yp = (const float4*)d_in[0];
    const float4* yt = (const float4*)d_in[1];
    const float* lsv = (const float*)d_in[2];
    const float* lsu = (const float*)d_in[3];
    float* out = (float*)d_out;

    long long n = (long long)in_sizes[0];   // 33554432, divisible by 4
    int n4 = (int)(n / 4);                  // 8388608 float4s per tensor
    float neg_inv_n = -1.0f / (float)n;

    hipMemsetAsync(d_out, 0, sizeof(float), stream);

    int block = 256;
    int grid  = 8192;   // 2.1M threads x 4 float4-pairs = 8388608, exact, no tail
    gnll_kernel<<<grid, block, 0, stream>>>(yp, yt, lsv, lsu, out, n4, neg_inv_n);
}

// Round 6
// 51.679 us; speedup vs baseline: 2.3547x; 2.3547x over previous
//
#include <hip/hip_runtime.h>
#include <math.h>

// GaussianNLLLoss: out = -mean( c0 + log(normcdf(-lambda*resid/sigma)) - resid^2/(2*sigma2) )
// R6: two-stage reduction, ZERO same-address atomics.
// R5 lesson: dur scales with block count at fixed work -> same-address
// device-scope atomicAdd serializes (~10ns each at the coherence point).
// 8192 atomics ~= +60us; even 2048 ~= +20us hidden in every prior round.
// Stage 1: 2048 blocks, partial per block -> d_ws[blockIdx.x].
// Stage 2: one block sums 2048 partials, writes -mean.

__device__ __forceinline__ float ll_elem(float r, float karg, float nk2, float inv2s2) {
    float r2 = r * r;
    float x  = karg * r;
    float ax = fabsf(x);
    float t  = __builtin_amdgcn_rcpf(fmaf(0.3275911f, ax, 1.0f));  // v_rcp_f32
    float p  = fmaf(t, 1.061405429f, -1.453152027f);
    p = fmaf(t, p, 1.421413741f);
    p = fmaf(t, p, -0.284496736f);
    p = fmaf(t, p, 0.254829592f);
    p *= t;
    float e  = __expf(nk2 * r2);                 // exp(-x^2), reusing r^2
    float ea = fmaf(-p, e, 1.0f);                // erf(|x|)  (A&S 7.1.26, |err|<1.5e-7)
    float ev = copysignf(ea, x);                 // erf(x)
    return __logf(fmaf(0.5f, ev, 0.5f)) - r2 * inv2s2;  // log(ncdf) - r^2/(2s2)
}

__global__ __launch_bounds__(256) void gnll_stage1(
    const float4* __restrict__ yp, const float4* __restrict__ yt,
    const float* __restrict__ lsv, const float* __restrict__ lsu,
    float* __restrict__ partials, int n4)
{
    const float std_v  = __expf(lsv[0]);
    const float std_u  = __expf(lsu[0]);
    const float sigma2 = std_v * std_v + std_u * std_u;
    const float sigma  = sqrtf(sigma2);
    const float llamda = std_u / std_v;
    const float karg   = -llamda / sigma * 0.70710678118654752f;  // *r -> erf arg
    const float nk2    = -karg * karg;                            // *r^2 -> -x^2
    const float c0     = -0.5f * logf(1.57079632679489662f)
                         - 0.5f * logf(sigma2);
    const float inv2s2 = 0.5f / sigma2;

    float acc = 0.0f;
    int   cnt = 0;
    const int tid = blockIdx.x * blockDim.x + threadIdx.x;
    const int nth = gridDim.x * blockDim.x;

    float4 pA0, pA1, pA2, pA3, tA0, tA1, tA2, tA3;
    float4 pB0, pB1, pB2, pB3, tB0, tB1, tB2, tB3;

#define LOAD_A(g) { int b_ = (g) * nth * 4 + tid;                                   \
    pA0 = yp[b_]; pA1 = yp[b_ + nth]; pA2 = yp[b_ + 2*nth]; pA3 = yp[b_ + 3*nth];   \
    tA0 = yt[b_]; tA1 = yt[b_ + nth]; tA2 = yt[b_ + 2*nth]; tA3 = yt[b_ + 3*nth]; }
#define LOAD_B(g) { int b_ = (g) * nth * 4 + tid;                                   \
    pB0 = yp[b_]; pB1 = yp[b_ + nth]; pB2 = yp[b_ + 2*nth]; pB3 = yp[b_ + 3*nth];   \
    tB0 = yt[b_]; tB1 = yt[b_ + nth]; tB2 = yt[b_ + 2*nth]; tB3 = yt[b_ + 3*nth]; }
#define COMP1(P, T) { float s_ =                                                    \
      ll_elem(T.x - P.x, karg, nk2, inv2s2) + ll_elem(T.y - P.y, karg, nk2, inv2s2) \
    + ll_elem(T.z - P.z, karg, nk2, inv2s2) + ll_elem(T.w - P.w, karg, nk2, inv2s2);\
    acc += s_; }
#define COMP_A { COMP1(pA0, tA0) COMP1(pA1, tA1) COMP1(pA2, tA2) COMP1(pA3, tA3) cnt += 16; }
#define COMP_B { COMP1(pB0, tB0) COMP1(pB1, tB1) COMP1(pB2, tB2) COMP1(pB3, tB3) cnt += 16; }

    const int ngroups = n4 / (nth * 4);   // 4 for the bench shape
    if (ngroups > 0) {
        LOAD_A(0)
        int g = 0;
        for (; g + 2 < ngroups; g += 2) {
            LOAD_B(g + 1)
            COMP_A
            LOAD_A(g + 2)
            COMP_B
        }
        if (g + 1 < ngroups) {
            LOAD_B(g + 1)
            COMP_A
            COMP_B
        } else {
            COMP_A
        }
    }

    // Tail (none at the bench shape)
    for (int i = ngroups * nth * 4 + tid; i < n4; i += nth) {
        float4 p = yp[i];
        float4 t = yt[i];
        acc += ll_elem(t.x - p.x, karg, nk2, inv2s2)
             + ll_elem(t.y - p.y, karg, nk2, inv2s2)
             + ll_elem(t.z - p.z, karg, nk2, inv2s2)
             + ll_elem(t.w - p.w, karg, nk2, inv2s2);
        cnt += 4;
    }

    acc = fmaf((float)cnt, c0, acc);

    // wave64 butterfly reduce
    #pragma unroll
    for (int off = 32; off > 0; off >>= 1)
        acc += __shfl_down(acc, off, 64);

    __shared__ float ws[4];
    int lane = threadIdx.x & 63;
    int wid  = threadIdx.x >> 6;
    if (lane == 0) ws[wid] = acc;
    __syncthreads();
    if (threadIdx.x == 0)
        partials[blockIdx.x] = (ws[0] + ws[1]) + (ws[2] + ws[3]);
}

__global__ __launch_bounds__(256) void gnll_stage2(
    const float* __restrict__ partials, float* __restrict__ out,
    int nparts, float neg_inv_n)
{
    float acc = 0.0f;
    for (int i = threadIdx.x; i < nparts; i += 256)
        acc += partials[i];

    #pragma unroll
    for (int off = 32; off > 0; off >>= 1)
        acc += __shfl_down(acc, off, 64);

    __shared__ float ws[4];
    int lane = threadIdx.x & 63;
    int wid  = threadIdx.x >> 6;
    if (lane == 0) ws[wid] = acc;
    __syncthreads();
    if (threadIdx.x == 0)
        out[0] = ((ws[0] + ws[1]) + (ws[2] + ws[3])) * neg_inv_n;
}

extern "C" void kernel_launch(void* const* d_in, const int* in_sizes, int n_in,
                              void* d_out, int out_size, void* d_ws, size_t ws_size,
                              hipStream_t stream) {
    const float4* yp = (const float4*)d_in[0];
    const float4* yt = (const float4*)d_in[1];
    const float* lsv = (const float*)d_in[2];
    const float* lsu = (const float*)d_in[3];
    float* out = (float*)d_out;
    float* partials = (float*)d_ws;   // 2048 floats = 8 KB scratch

    long long n = (long long)in_sizes[0];   // 33554432, divisible by 4
    int n4 = (int)(n / 4);
    float neg_inv_n = -1.0f / (float)n;

    const int block = 256;
    const int grid  = 2048;  // ngroups = 4 at bench shape, no tail
    gnll_stage1<<<grid, block, 0, stream>>>(yp, yt, lsv, lsu, partials, n4);
    gnll_stage2<<<1, block, 0, stream>>>(partials, out, grid, neg_inv_n);
}